// Round 15
// baseline (98.115 us; speedup 1.0000x reference)
//
#include <hip/hip_runtime.h>

#define HIDDEN 4096
#define RANK   256
#define G      16
#define ENTH   512    // 8 waves/block, 1 block/CU (LDS-forced)
#define TB     8      // tokens per wave; 8 waves * 8 = 64 tokens/block

typedef _Float16 h2d __attribute__((ext_vector_type(2)));
typedef float    f4v __attribute__((ext_vector_type(4)));

__device__ __forceinline__ unsigned int pkf16(float a, float b) {
    auto h = __builtin_amdgcn_cvt_pkrtz(a, b);
    return __builtin_bit_cast(unsigned int, h);
}
__device__ __forceinline__ float dot2(unsigned int a, unsigned int b, float c) {
    return __builtin_amdgcn_fdot2(__builtin_bit_cast(h2d, a),
                                  __builtin_bit_cast(h2d, b), c, false);
}
__device__ __forceinline__ float4 f4add(float4 a, float4 b) {
    return make_float4(a.x + b.x, a.y + b.y, a.z + b.z, a.w + b.w);
}

// ---------------------------------------------------------------------------
// pack: Mp[pr*256 + k] = {f16 M[2pr][k], f16 M[2pr+1][k]}   (128 KB, once)
// ---------------------------------------------------------------------------
__global__ __launch_bounds__(256)
void mora_pack(const float* __restrict__ Mg, unsigned int* __restrict__ Mp) {
    const int idx = blockIdx.x * 256 + threadIdx.x;    // 0..32767
    const int pr  = idx >> 8;
    const int k   = idx & 255;
    Mp[idx] = pkf16(Mg[(size_t)(2 * pr) * RANK + k],
                    Mg[(size_t)(2 * pr + 1) * RANK + k]);
}

// ---------------------------------------------------------------------------
// fused, software-pipelined. Barrier ONLY after M staging. Wave owns 8
// tokens in 4 stages of 2: stage s+1's 32 x-loads are issued into named
// staged registers BEFORE expand(s), so stage-s NT stores overlap stage-
// (s+1) reads — both HBM directions active continuously.
// Dynamic LDS: [0,131072) M f16-pairs; [131072,139264) ostage f32[8][256].
// ---------------------------------------------------------------------------
__global__ __launch_bounds__(ENTH, 2)
void mora_fused(const float* __restrict__ x,          // [T, HIDDEN]
                const unsigned int* __restrict__ Mp,  // [128][256] f16 pairs
                float* __restrict__ out)              // [T, HIDDEN]
{
    extern __shared__ unsigned char smem[];
    unsigned int* Ml = (unsigned int*)smem;            // [128][256]
    float* ostage    = (float*)(smem + 131072);        // [8][256]

    const int  tid  = threadIdx.x;
    const int  w    = tid >> 6;    // wave 0..7
    const int  l    = tid & 63;
    const long tok0 = (long)blockIdx.x * 64 + (long)w * TB;

    // ---- stage full packed M -> LDS (8192 uint4, coalesced, linear) ----
    {
        const uint4* src = (const uint4*)Mp;
        uint4* dst = (uint4*)Ml;
        #pragma unroll
        for (int i = 0; i < 16; ++i)
            dst[tid + (i << 9)] = src[tid + (i << 9)];
    }

    // staged x-loads for one 2-token stage: 32 float4 (deferred adds)
    float4 stg[32];
    #define ISSUE(s)                                                        \
        {                                                                   \
            _Pragma("unroll")                                               \
            for (int tt = 0; tt < 2; ++tt) {                                \
                const float4* xr =                                          \
                    (const float4*)(x + (tok0 + 2 * (s) + tt) * HIDDEN) + l;\
                _Pragma("unroll")                                           \
                for (int j = 0; j < 16; ++j)                                \
                    stg[tt * 16 + j] = xr[j * 64];                          \
            }                                                               \
        }

    ISSUE(0);
    __syncthreads();   // drains only M staging (+ stage-0 issue overlap)

    const uint4* Ml4 = (const uint4*)Ml + l;   // pair-row stride = 64 uint4
    float* ost = ostage + w * RANK;            // per-wave private

    #pragma unroll
    for (int s = 0; s < 4; ++s) {
        // ---- reduce staged -> packed comp (tree; waits this stage's loads)
        unsigned int cp0[2], cp1[2];
        #pragma unroll
        for (int tt = 0; tt < 2; ++tt) {
            float4 a0 = f4add(stg[tt*16+ 0], stg[tt*16+ 1]);
            float4 a1 = f4add(stg[tt*16+ 2], stg[tt*16+ 3]);
            float4 a2 = f4add(stg[tt*16+ 4], stg[tt*16+ 5]);
            float4 a3 = f4add(stg[tt*16+ 6], stg[tt*16+ 7]);
            float4 a4 = f4add(stg[tt*16+ 8], stg[tt*16+ 9]);
            float4 a5 = f4add(stg[tt*16+10], stg[tt*16+11]);
            float4 a6 = f4add(stg[tt*16+12], stg[tt*16+13]);
            float4 a7 = f4add(stg[tt*16+14], stg[tt*16+15]);
            a0 = f4add(a0, a1); a2 = f4add(a2, a3);
            a4 = f4add(a4, a5); a6 = f4add(a6, a7);
            a0 = f4add(a0, a2); a4 = f4add(a4, a6);
            a0 = f4add(a0, a4);
            cp0[tt] = pkf16(a0.x, a0.y);
            cp1[tt] = pkf16(a0.z, a0.w);
        }

        // ---- issue next stage's reads NOW (fly during expand + stores) ----
        if (s < 3) ISSUE(s + 1);

        // ---- expand 2 tokens: one shared M sweep from LDS ----
        float acc[2][4];
        #pragma unroll
        for (int tt = 0; tt < 2; ++tt) {
            acc[tt][0] = 0.f; acc[tt][1] = 0.f;
            acc[tt][2] = 0.f; acc[tt][3] = 0.f;
        }

        #pragma unroll 4
        for (int i = 0; i < 32; ++i) {
            const uint4 m0 = Ml4[(4 * i + 0) << 6];   // 1 KiB b128, no conflict
            const uint4 m1 = Ml4[(4 * i + 1) << 6];
            const uint4 m2 = Ml4[(4 * i + 2) << 6];
            const uint4 m3 = Ml4[(4 * i + 3) << 6];
            #pragma unroll
            for (int tt = 0; tt < 2; ++tt) {
                const unsigned s0 = (unsigned)__builtin_amdgcn_readlane((int)cp0[tt], 2 * i);
                const unsigned s1 = (unsigned)__builtin_amdgcn_readlane((int)cp1[tt], 2 * i);
                const unsigned s2 = (unsigned)__builtin_amdgcn_readlane((int)cp0[tt], 2 * i + 1);
                const unsigned s3 = (unsigned)__builtin_amdgcn_readlane((int)cp1[tt], 2 * i + 1);
                acc[tt][0] = dot2(s0, m0.x, acc[tt][0]);
                acc[tt][1] = dot2(s0, m0.y, acc[tt][1]);
                acc[tt][2] = dot2(s0, m0.z, acc[tt][2]);
                acc[tt][3] = dot2(s0, m0.w, acc[tt][3]);
                acc[tt][0] = dot2(s1, m1.x, acc[tt][0]);
                acc[tt][1] = dot2(s1, m1.y, acc[tt][1]);
                acc[tt][2] = dot2(s1, m1.z, acc[tt][2]);
                acc[tt][3] = dot2(s1, m1.w, acc[tt][3]);
                acc[tt][0] = dot2(s2, m2.x, acc[tt][0]);
                acc[tt][1] = dot2(s2, m2.y, acc[tt][1]);
                acc[tt][2] = dot2(s2, m2.z, acc[tt][2]);
                acc[tt][3] = dot2(s2, m2.w, acc[tt][3]);
                acc[tt][0] = dot2(s3, m3.x, acc[tt][0]);
                acc[tt][1] = dot2(s3, m3.y, acc[tt][1]);
                acc[tt][2] = dot2(s3, m3.z, acc[tt][2]);
                acc[tt][3] = dot2(s3, m3.w, acc[tt][3]);
            }
        }

        // ---- per-wave restage + NT coalesced splat stores ----
        #pragma unroll
        for (int tt = 0; tt < 2; ++tt) {
            ((float4*)ost)[l] =
                make_float4(acc[tt][0], acc[tt][1], acc[tt][2], acc[tt][3]);
            f4v* orow = (f4v*)(out + (tok0 + 2 * s + tt) * HIDDEN);
            #pragma unroll
            for (int sj = 0; sj < 16; ++sj) {
                const float v = ost[(sj << 4) + (l >> 2)];  // 4-lane bcast, free
                const f4v sp = {v, v, v, v};
                __builtin_nontemporal_store(sp, orow + (sj << 6) + l);
            }
        }
    }
    #undef ISSUE
}

extern "C" void kernel_launch(void* const* d_in, const int* in_sizes, int n_in,
                              void* d_out, int out_size, void* d_ws, size_t ws_size,
                              hipStream_t stream) {
    const float* x = (const float*)d_in[0];
    const float* M = (const float*)d_in[1];
    float* out     = (float*)d_out;

    unsigned int* Mp = (unsigned int*)d_ws;    // 128 KiB packed M

    const int T = in_sizes[0] / HIDDEN;        // 16384 tokens
    const int smem_bytes = 139264;             // 128 KiB M + 8 KiB ostage

    (void)hipFuncSetAttribute((const void*)mora_fused,
                              hipFuncAttributeMaxDynamicSharedMemorySize,
                              smem_bytes);

    hipLaunchKernelGGL(mora_pack, dim3(128), dim3(256), 0, stream, M, Mp);
    hipLaunchKernelGGL(mora_fused, dim3(T / 64), dim3(ENTH), smem_bytes,
                       stream, x, Mp, out);
}